// Round 1
// baseline (450.137 us; speedup 1.0000x reference)
//
#include <hip/hip_runtime.h>
#include <math.h>

// Problem constants (B=1)
// N=512, CS=384, CZ=128, G=16, CH=48, H=8, PQ=8, PV=12, NF=4, CZ4=32
// feats dim = 384 (o) + 96*3 (o_pt xyz) + 96 (norm) + 256 (o_pair) = 1024

// ---- workspace layout (floats) ----
#define OFF_PROJ 0
#define SZ_PROJ (512*1632)
#define OFF_QW (OFF_PROJ + SZ_PROJ)
#define SZ_QW (8*512*192)
#define OFF_KST (OFF_QW + SZ_QW)
#define OFF_V (OFF_KST + SZ_QW)
#define SZ_V (512*384)
#define OFF_VP (OFF_V + SZ_V)
#define SZ_VP (512*288)
#define OFF_A (OFF_VP + SZ_VP)
#define SZ_A (8*512*512)
#define OFF_PZ (OFF_A + SZ_A)
#define SZ_PZ (512*512*32)
#define OFF_FEATS (OFF_PZ + SZ_PZ)
#define SZ_FEATS (512*1024)
// total = 13,762,560 floats = 55.1 MB

// ============ K1: s @ [wq|wkv|wkvp] + bias -> proj (512 x 1632) ============
// tile 64x64, 4x4 per thread, k-tile 16
__global__ __launch_bounds__(256) void proj_kernel(
    const float* __restrict__ s, const float* __restrict__ wq, const float* __restrict__ bq,
    const float* __restrict__ wkv, const float* __restrict__ bkv,
    const float* __restrict__ wkvp, const float* __restrict__ bkvp,
    float* __restrict__ proj)
{
  __shared__ float sA[64][20];
  __shared__ float sB[16][68];
  int ct = blockIdx.x;          // 26 col tiles of 64 (last is half)
  int i0 = blockIdx.y * 64;
  int col0 = ct * 64;
  const float* W; const float* bias; int wld, wcol0;
  if (col0 < 384)       { W = wq;   bias = bq;   wld = 384; wcol0 = col0; }
  else if (col0 < 1152) { W = wkv;  bias = bkv;  wld = 768; wcol0 = col0 - 384; }
  else                  { W = wkvp; bias = bkvp; wld = 480; wcol0 = col0 - 1152; }
  int t = threadIdx.x;
  int tr4 = (t >> 4) * 4;
  int tc4 = (t & 15) * 4;
  float acc[4][4];
  #pragma unroll
  for (int q = 0; q < 4; q++)
    #pragma unroll
    for (int p = 0; p < 4; p++) acc[q][p] = 0.f;
  bool wfull = (wcol0 + 64 <= wld);
  for (int kt = 0; kt < 384; kt += 16){
    {
      int r = t >> 2, k0 = (t & 3) * 4;
      float4 v = *(const float4*)(s + (i0 + r)*384 + kt + k0);
      *(float4*)&sA[r][k0] = v;
    }
    {
      int r = t >> 4, c0 = (t & 15) * 4;
      if (wfull){
        float4 v = *(const float4*)(W + (kt + r)*wld + wcol0 + c0);
        *(float4*)&sB[r][c0] = v;
      } else {
        #pragma unroll
        for (int u = 0; u < 4; u++){
          int wc = wcol0 + c0 + u; if (wc >= wld) wc = wld - 1;
          sB[r][c0+u] = W[(kt + r)*wld + wc];
        }
      }
    }
    __syncthreads();
    #pragma unroll
    for (int k = 0; k < 16; k++){
      float4 bv = *(const float4*)&sB[k][tc4];
      float av[4];
      #pragma unroll
      for (int q = 0; q < 4; q++) av[q] = sA[tr4+q][k];
      #pragma unroll
      for (int q = 0; q < 4; q++){
        acc[q][0] = fmaf(av[q], bv.x, acc[q][0]);
        acc[q][1] = fmaf(av[q], bv.y, acc[q][1]);
        acc[q][2] = fmaf(av[q], bv.z, acc[q][2]);
        acc[q][3] = fmaf(av[q], bv.w, acc[q][3]);
      }
    }
    __syncthreads();
  }
  #pragma unroll
  for (int q = 0; q < 4; q++){
    int row = i0 + tr4 + q;
    #pragma unroll
    for (int p = 0; p < 4; p++){
      int col = col0 + tc4 + p;
      if (col < 1632){
        proj[row*1632 + col] = acc[q][p] + bias[wcol0 + tc4 + p];
      }
    }
  }
}

// ============ K2: per-node rotation + pack Qw/Kst (192-d), V, VP ============
__global__ __launch_bounds__(128) void node_kernel(
    const float* __restrict__ proj, const float* __restrict__ rotvec,
    const float* __restrict__ lfa, const float* __restrict__ gwts, const float* __restrict__ fwts,
    float* __restrict__ Qw, float* __restrict__ Kst, float* __restrict__ V, float* __restrict__ VP)
{
  int i = blockIdx.x, t = threadIdx.x;
  const float* pr = proj + i*1632;
  float rx = rotvec[i*3], ry = rotvec[i*3+1], rz = rotvec[i*3+2];
  float nrm = sqrtf(rx*rx + ry*ry + rz*rz);
  float angle = nrm + 1e-8f;
  float inv = 1.0f / fmaxf(nrm, 1e-12f);
  float ax = rx*inv, ay = ry*inv, az = rz*inv;
  // softmax(freq_weights)
  float f0 = fwts[0], f1 = fwts[1], f2 = fwts[2], f3 = fwts[3];
  float mfw = fmaxf(fmaxf(f0,f1), fmaxf(f2,f3));
  float e0 = expf(f0-mfw), e1 = expf(f1-mfw), e2 = expf(f2-mfw), e3 = expf(f3-mfw);
  float esum = e0+e1+e2+e3;
  float fw[4] = {e0/esum, e1/esum, e2/esum, e3/esum};
  // base freqs 8^{-i/2} (min with 1.0 is identity here)
  float fq[4] = { 1.0f*expf(lfa[0]), 0.35355339059327373f*expf(lfa[1]),
                  0.125f*expf(lfa[2]), 0.04419417382415922f*expf(lfa[3]) };
  int h = t >> 4, g = t & 15;
  float gw = log1pf(expf(gwts[g])) * 0.25f;  // softplus * sqrt(1/16)
  float q0 = pr[h*48 + g*3 + 0], q1 = pr[h*48 + g*3 + 1], q2 = pr[h*48 + g*3 + 2];
  float k0 = pr[384 + h*96 + g*3 + 0], k1 = pr[384 + h*96 + g*3 + 1], k2 = pr[384 + h*96 + g*3 + 2];
  #pragma unroll
  for (int f = 0; f < 4; f++){
    float th = angle * fq[f];
    float sn = sinf(th), cs = cosf(th), omc = 1.0f - cs;
    // R = cos I + sin K + (1-cos) a a^T  (unit axis => equals I + sin K + (1-cos) K^2)
    float r00 = cs + omc*ax*ax,       r01 = omc*ax*ay - sn*az,  r02 = omc*ax*az + sn*ay;
    float r10 = omc*ay*ax + sn*az,    r11 = cs + omc*ay*ay,     r12 = omc*ay*az - sn*ax;
    float r20 = omc*az*ax - sn*ay,    r21 = omc*az*ay + sn*ax,  r22 = cs + omc*az*az;
    float qr0 = r00*q0 + r01*q1 + r02*q2;
    float qr1 = r10*q0 + r11*q1 + r12*q2;
    float qr2 = r20*q0 + r21*q1 + r22*q2;
    float kr0 = r00*k0 + r01*k1 + r02*k2;
    float kr1 = r10*k0 + r11*k1 + r12*k2;
    float kr2 = r20*k0 + r21*k1 + r22*k2;
    float sc = fw[f] * gw * 0.57735026918962576f;  // fold freq_w * group_w * 1/sqrt(3)
    int base = (h*512 + i)*192 + (g*4 + f)*3;
    Qw[base+0] = qr0*sc; Qw[base+1] = qr1*sc; Qw[base+2] = qr2*sc;
    Kst[base+0] = kr0;   Kst[base+1] = kr1;   Kst[base+2] = kr2;
  }
  // pack V: v[j][h*48+c] = proj[384 + h*96 + 48 + c]
  for (int c = t; c < 384; c += 128){
    int hh = c / 48, cc = c % 48;
    V[i*384 + c] = pr[384 + hh*96 + 48 + cc];
  }
  // pack VP: vp[j][(h*12+p)*3 + c3] = proj[1152 + c3*160 + h*20 + 8 + p]
  for (int qx = t; qx < 288; qx += 128){
    int ch = qx / 3, c3 = qx % 3;
    int hh = ch / 12, p = ch % 12;
    VP[i*288 + qx] = pr[1152 + c3*160 + hh*20 + 8 + p];
  }
}

// ============ K3: z read once -> biasS (sqrt(1/3) folded, [h][i][j]) + PZ [i][j][32] ============
// block = (jt in 0..1, i); 256 threads: wave cg owns 10 channels, lane jg owns 4 j (stride 64)
__global__ __launch_bounds__(256) void zproj_kernel(
    const float* __restrict__ z, const float* __restrict__ wb, const float* __restrict__ bb,
    const float* __restrict__ wdz, const float* __restrict__ bdz,
    float* __restrict__ biasS, float* __restrict__ PZ)
{
  __shared__ float zs[256][33];
  __shared__ float Wl[40][128];
  int i = blockIdx.y;
  int jt = blockIdx.x;               // j base = jt*256
  int t = threadIdx.x;
  int cg = t >> 6, jg = t & 63;
  for (int e = t; e < 40*128; e += 256){
    int c = e >> 7, k = e & 127;
    Wl[c][k] = (c < 8) ? wb[k*8 + c] : wdz[k*32 + (c - 8)];
  }
  float acc[10][4];
  #pragma unroll
  for (int cc = 0; cc < 10; cc++)
    #pragma unroll
    for (int q = 0; q < 4; q++) acc[cc][q] = 0.f;
  for (int kt = 0; kt < 4; kt++){
    __syncthreads();
    #pragma unroll
    for (int r = 0; r < 8; r++){
      int idx = t + 256*r;
      int jr = idx >> 3, k4 = idx & 7;
      float4 v = *(const float4*)(z + (size_t)(i*512 + jt*256 + jr)*128 + kt*32 + k4*4);
      zs[jr][k4*4+0] = v.x; zs[jr][k4*4+1] = v.y; zs[jr][k4*4+2] = v.z; zs[jr][k4*4+3] = v.w;
    }
    __syncthreads();
    #pragma unroll 4
    for (int k = 0; k < 32; k++){
      float zv[4];
      #pragma unroll
      for (int q = 0; q < 4; q++) zv[q] = zs[q*64 + jg][k];
      #pragma unroll
      for (int cc = 0; cc < 10; cc++){
        float wv = Wl[cg*10 + cc][kt*32 + k];
        #pragma unroll
        for (int q = 0; q < 4; q++) acc[cc][q] = fmaf(zv[q], wv, acc[cc][q]);
      }
    }
  }
  __syncthreads();   // done with z tile; reuse zs for pair_z transpose staging
  #pragma unroll
  for (int cc = 0; cc < 10; cc++){
    int ch = cg*10 + cc;
    if (ch < 8){
      float bv = bb[ch];
      #pragma unroll
      for (int q = 0; q < 4; q++){
        int j = jt*256 + q*64 + jg;
        biasS[(size_t)ch*262144 + i*512 + j] = 0.57735026918962576f * (acc[cc][q] + bv);
      }
    } else {
      int c = ch - 8;
      float bv = bdz[c];
      #pragma unroll
      for (int q = 0; q < 4; q++){
        zs[q*64 + jg][c] = acc[cc][q] + bv;
      }
    }
  }
  __syncthreads();
  #pragma unroll
  for (int r = 0; r < 8; r++){
    int idx = t + 256*r;
    int jr = idx >> 3, c4 = idx & 7;
    float4 v;
    v.x = zs[jr][c4*4+0]; v.y = zs[jr][c4*4+1]; v.z = zs[jr][c4*4+2]; v.w = zs[jr][c4*4+3];
    *(float4*)(PZ + (size_t)(i*512 + jt*256 + jr)*32 + c4*4) = v;
  }
}

// ============ K4: scores (192-d dot) + bias + mask + softmax, in-place over biasS -> a ============
// block: (i-tile of 16, h); wave ig owns 4 i-rows, lane jl owns j within each 64-j tile
__global__ __launch_bounds__(256) void scores_kernel(
    const float* __restrict__ Qw, const float* __restrict__ Kst,
    const float* __restrict__ mask, float* A)
{
  __shared__ float Qs[16][196];
  __shared__ float Ks[64][196];
  int i0 = blockIdx.x * 16;
  int h = blockIdx.y;
  int t = threadIdx.x;
  int ig = t >> 6, jl = t & 63;
  for (int e = t; e < 16*48; e += 256){
    int r = e / 48, k4 = e % 48;
    float4 v = *(const float4*)(Qw + (size_t)(h*512 + i0 + r)*192 + k4*4);
    *(float4*)&Qs[r][k4*4] = v;
  }
  float lg[4][8];
  for (int jtile = 0; jtile < 8; jtile++){
    __syncthreads();
    for (int e = t; e < 64*48; e += 256){
      int r = e / 48, k4 = e % 48;
      float4 v = *(const float4*)(Kst + (size_t)(h*512 + jtile*64 + r)*192 + k4*4);
      *(float4*)&Ks[r][k4*4] = v;
    }
    __syncthreads();
    float acc[4] = {0.f, 0.f, 0.f, 0.f};
    #pragma unroll 8
    for (int k4 = 0; k4 < 48; k4++){
      float4 kv = *(const float4*)&Ks[jl][k4*4];
      #pragma unroll
      for (int q = 0; q < 4; q++){
        float4 qv = *(const float4*)&Qs[ig*4+q][k4*4];
        acc[q] = fmaf(qv.x, kv.x, acc[q]);
        acc[q] = fmaf(qv.y, kv.y, acc[q]);
        acc[q] = fmaf(qv.z, kv.z, acc[q]);
        acc[q] = fmaf(qv.w, kv.w, acc[q]);
      }
    }
    int j = jtile*64 + jl;
    float mj = mask[j];
    #pragma unroll
    for (int q = 0; q < 4; q++){
      int i = i0 + ig*4 + q;
      float b = A[(size_t)(h*512 + i)*512 + j];   // biasS (sqrt(1/3) already folded)
      float mi = mask[i];
      lg[q][jtile] = acc[q] + b + 100000.0f*(mi*mj - 1.0f);
    }
  }
  // softmax across this wave's 64 lanes x 8 tiles (rows are wave-private => in-place is safe)
  #pragma unroll
  for (int q = 0; q < 4; q++){
    float m = lg[q][0];
    #pragma unroll
    for (int tl = 1; tl < 8; tl++) m = fmaxf(m, lg[q][tl]);
    for (int off = 32; off > 0; off >>= 1) m = fmaxf(m, __shfl_xor(m, off));
    float ssum = 0.f;
    #pragma unroll
    for (int tl = 0; tl < 8; tl++){ lg[q][tl] = expf(lg[q][tl] - m); ssum += lg[q][tl]; }
    for (int off = 32; off > 0; off >>= 1) ssum += __shfl_xor(ssum, off);
    float invs = 1.0f / ssum;
    int i = i0 + ig*4 + q;
    #pragma unroll
    for (int tl = 0; tl < 8; tl++){
      A[(size_t)(h*512 + i)*512 + tl*64 + jl] = lg[q][tl] * invs;
    }
  }
}

// ============ K5: per-i accumulation of o / o_pt / o_pair + norms -> feats (512 x 1024) ============
// 928 channels: [0,384) o from V; [384,672) o_pt from VP; [672,928) o_pair from PZ
__global__ __launch_bounds__(256) void accum_kernel(
    const float* __restrict__ A, const float* __restrict__ V, const float* __restrict__ VP,
    const float* __restrict__ PZ, float* __restrict__ feats)
{
  __shared__ float a_s[8][64];
  __shared__ float opt_s[288];
  int i = blockIdx.x, t = threadIdx.x;
  int chs[4]; const float* bases[4]; int strides[4]; int hh[4];
  #pragma unroll
  for (int q = 0; q < 4; q++){
    int ch = t + q*256;
    chs[q] = ch;
    if (ch < 384){ hh[q] = ch/48; bases[q] = V + ch; strides[q] = 384; }
    else if (ch < 672){ int qq = ch - 384; hh[q] = qq/36; bases[q] = VP + qq; strides[q] = 288; }
    else if (ch < 928){ int qq = ch - 672; hh[q] = qq/32; bases[q] = PZ + (size_t)i*512*32 + (qq & 31); strides[q] = 32; }
    else { hh[q] = 0; bases[q] = V; strides[q] = 0; }   // dummy lanes (t>=160, q==3)
  }
  float acc[4] = {0.f, 0.f, 0.f, 0.f};
  for (int jtile = 0; jtile < 8; jtile++){
    __syncthreads();
    #pragma unroll
    for (int r = 0; r < 2; r++){
      int e = t + r*256;
      int eh = e >> 6, jj = e & 63;
      a_s[eh][jj] = A[(size_t)(eh*512 + i)*512 + jtile*64 + jj];
    }
    __syncthreads();
    #pragma unroll 4
    for (int jj = 0; jj < 64; jj++){
      int j = jtile*64 + jj;
      #pragma unroll
      for (int q = 0; q < 4; q++){
        acc[q] = fmaf(a_s[hh[q]][jj], bases[q][(size_t)j * strides[q]], acc[q]);
      }
    }
  }
  #pragma unroll
  for (int q = 0; q < 4; q++){
    int ch = chs[q];
    if (ch < 384){ feats[(size_t)i*1024 + ch] = acc[q]; }
    else if (ch < 672){ opt_s[ch - 384] = acc[q]; }
    else if (ch < 928){ feats[(size_t)i*1024 + 768 + (ch - 672)] = acc[q]; }
  }
  __syncthreads();
  if (t < 96){
    float x = opt_s[t*3+0], y = opt_s[t*3+1], zz = opt_s[t*3+2];
    feats[(size_t)i*1024 + 384 + t] = x;
    feats[(size_t)i*1024 + 480 + t] = y;
    feats[(size_t)i*1024 + 576 + t] = zz;
    feats[(size_t)i*1024 + 672 + t] = sqrtf(x*x + y*y + zz*zz + 1e-8f);
  }
}

// ============ K6: out = feats @ wout + bout  (512x1024 @ 1024x384) ============
__global__ __launch_bounds__(256) void out_kernel(
    const float* __restrict__ feats, const float* __restrict__ wout, const float* __restrict__ bout,
    float* __restrict__ out)
{
  __shared__ float sA[32][36];
  __shared__ float sB[32][36];
  int c0 = blockIdx.x * 32;
  int i0 = blockIdx.y * 32;
  int t = threadIdx.x;
  int tr2 = (t >> 4) * 2, tc2 = (t & 15) * 2;
  float a00=0.f, a01=0.f, a10=0.f, a11=0.f;
  for (int kt = 0; kt < 1024; kt += 32){
    {
      int r = t >> 3, k0 = (t & 7) * 4;
      float4 v = *(const float4*)(feats + (size_t)(i0 + r)*1024 + kt + k0);
      *(float4*)&sA[r][k0] = v;
      float4 w = *(const float4*)(wout + (size_t)(kt + r)*384 + c0 + k0);
      *(float4*)&sB[r][k0] = w;
    }
    __syncthreads();
    #pragma unroll
    for (int k = 0; k < 32; k++){
      float b0 = sB[k][tc2], b1 = sB[k][tc2+1];
      float a0 = sA[tr2][k], a1 = sA[tr2+1][k];
      a00 = fmaf(a0,b0,a00); a01 = fmaf(a0,b1,a01);
      a10 = fmaf(a1,b0,a10); a11 = fmaf(a1,b1,a11);
    }
    __syncthreads();
  }
  int c = c0 + tc2, r = i0 + tr2;
  float bo0 = bout[c], bo1 = bout[c+1];
  out[(size_t)r*384 + c]       = a00 + bo0;
  out[(size_t)r*384 + c + 1]   = a01 + bo1;
  out[(size_t)(r+1)*384 + c]   = a10 + bo0;
  out[(size_t)(r+1)*384 + c+1] = a11 + bo1;
}

extern "C" void kernel_launch(void* const* d_in, const int* in_sizes, int n_in,
                              void* d_out, int out_size, void* d_ws, size_t ws_size,
                              hipStream_t stream)
{
  const float* s    = (const float*)d_in[0];
  const float* z    = (const float*)d_in[1];
  const float* rotv = (const float*)d_in[2];
  const float* mask = (const float*)d_in[3];
  const float* wq   = (const float*)d_in[4];
  const float* bq   = (const float*)d_in[5];
  const float* wkv  = (const float*)d_in[6];
  const float* bkv  = (const float*)d_in[7];
  const float* wkvp = (const float*)d_in[8];
  const float* bkvp = (const float*)d_in[9];
  const float* wb   = (const float*)d_in[10];
  const float* bb   = (const float*)d_in[11];
  const float* wdz  = (const float*)d_in[12];
  const float* bdz  = (const float*)d_in[13];
  const float* wout = (const float*)d_in[14];
  const float* bout = (const float*)d_in[15];
  const float* lfa  = (const float*)d_in[16];
  const float* gwts = (const float*)d_in[17];
  const float* fwts = (const float*)d_in[18];
  float* out = (float*)d_out;
  float* ws  = (float*)d_ws;

  float* proj  = ws + OFF_PROJ;
  float* Qw    = ws + OFF_QW;
  float* Kst   = ws + OFF_KST;
  float* V     = ws + OFF_V;
  float* VP    = ws + OFF_VP;
  float* A     = ws + OFF_A;     // biasS, overwritten in-place by softmax probs
  float* PZ    = ws + OFF_PZ;
  float* feats = ws + OFF_FEATS;

  proj_kernel  <<<dim3(26, 8),  256, 0, stream>>>(s, wq, bq, wkv, bkv, wkvp, bkvp, proj);
  node_kernel  <<<dim3(512),    128, 0, stream>>>(proj, rotv, lfa, gwts, fwts, Qw, Kst, V, VP);
  zproj_kernel <<<dim3(2, 512), 256, 0, stream>>>(z, wb, bb, wdz, bdz, A, PZ);
  scores_kernel<<<dim3(32, 8),  256, 0, stream>>>(Qw, Kst, mask, A);
  accum_kernel <<<dim3(512),    256, 0, stream>>>(A, V, VP, PZ, feats);
  out_kernel   <<<dim3(12, 16), 256, 0, stream>>>(feats, wout, bout, out);
}

// Round 2
// 422.322 us; speedup vs baseline: 1.0659x; 1.0659x over previous
//
#include <hip/hip_runtime.h>
#include <math.h>

// Problem constants (B=1)
// N=512, CS=384, CZ=128, G=16, CH=48, H=8, PQ=8, PV=12, NF=4, CZ4=32
// feats dim = 384 (o) + 96*3 (o_pt xyz) + 96 (norm) + 256 (o_pair) = 1024

// ---- workspace layout (floats) ----
#define OFF_PROJ 0
#define SZ_PROJ (512*1632)
#define OFF_QW (OFF_PROJ + SZ_PROJ)
#define SZ_QW (8*512*192)
#define OFF_KST (OFF_QW + SZ_QW)
#define OFF_V (OFF_KST + SZ_QW)
#define SZ_V (512*384)
#define OFF_VP (OFF_V + SZ_V)
#define SZ_VP (512*288)
#define OFF_A (OFF_VP + SZ_VP)
#define SZ_A (8*512*512)
#define OFF_FEATS (OFF_A + SZ_A)
#define SZ_FEATS (512*1024)
#define OFF_PART (OFF_FEATS + SZ_FEATS)
#define SZ_PART (8*512*384)
// total ~ 6.95M floats = 27.8 MB

// ============ K1: s @ [wq|wkv|wkvp] + bias -> proj (512 x 1632) ============
// block: 32 i x 64 c; s staged transposed in LDS once; W streamed from global.
__global__ __launch_bounds__(256) void proj_kernel(
    const float* __restrict__ s, const float* __restrict__ wq, const float* __restrict__ bq,
    const float* __restrict__ wkv, const float* __restrict__ bkv,
    const float* __restrict__ wkvp, const float* __restrict__ bkvp,
    float* __restrict__ proj)
{
  __shared__ float sT[384][34];
  int ct = blockIdx.x;          // 26 col tiles of 64
  int i0 = blockIdx.y * 32;
  int col0 = ct * 64;
  const float* W; const float* bias; int wld, wcol0;
  if (col0 < 384)       { W = wq;   bias = bq;   wld = 384; wcol0 = col0; }
  else if (col0 < 1152) { W = wkv;  bias = bkv;  wld = 768; wcol0 = col0 - 384; }
  else                  { W = wkvp; bias = bkvp; wld = 480; wcol0 = col0 - 1152; }
  int t = threadIdx.x;
  // stage s[i0..i0+32][0..384] transposed -> sT[k][i]; lane map i-fastest (LDS conflict-free)
  #pragma unroll
  for (int r = 0; r < 12; r++){
    int e = t + 256*r;
    int i = e & 31;
    int k4 = e >> 5;            // 0..95
    float4 v = *(const float4*)(s + (size_t)(i0 + i)*384 + k4*4);
    sT[k4*4+0][i] = v.x; sT[k4*4+1][i] = v.y; sT[k4*4+2][i] = v.z; sT[k4*4+3][i] = v.w;
  }
  __syncthreads();
  int cr = t & 15;
  int ipair = t >> 4;           // 16 i-pairs
  int ii = ipair * 2;
  int wc = wcol0 + cr*4;
  bool valid = (wc + 4 <= wld);
  int wcc = valid ? wc : (wld - 4);
  float acc[2][4];
  #pragma unroll
  for (int q = 0; q < 2; q++)
    #pragma unroll
    for (int p = 0; p < 4; p++) acc[q][p] = 0.f;
  #pragma unroll 4
  for (int k = 0; k < 384; k++){
    float2 a2 = *(const float2*)&sT[k][ii];
    float4 w4 = *(const float4*)(W + (size_t)k*wld + wcc);
    acc[0][0] = fmaf(a2.x, w4.x, acc[0][0]);
    acc[0][1] = fmaf(a2.x, w4.y, acc[0][1]);
    acc[0][2] = fmaf(a2.x, w4.z, acc[0][2]);
    acc[0][3] = fmaf(a2.x, w4.w, acc[0][3]);
    acc[1][0] = fmaf(a2.y, w4.x, acc[1][0]);
    acc[1][1] = fmaf(a2.y, w4.y, acc[1][1]);
    acc[1][2] = fmaf(a2.y, w4.z, acc[1][2]);
    acc[1][3] = fmaf(a2.y, w4.w, acc[1][3]);
  }
  if (valid){
    float4 bv = *(const float4*)(bias + wc);
    #pragma unroll
    for (int q = 0; q < 2; q++){
      int row = i0 + ii + q;
      float4 o;
      o.x = acc[q][0] + bv.x; o.y = acc[q][1] + bv.y;
      o.z = acc[q][2] + bv.z; o.w = acc[q][3] + bv.w;
      *(float4*)(proj + (size_t)row*1632 + col0 + cr*4) = o;
    }
  }
}

// ============ K2: per-node rotation + pack Qw/Kst (192-d), V, VP ============
__global__ __launch_bounds__(128) void node_kernel(
    const float* __restrict__ proj, const float* __restrict__ rotvec,
    const float* __restrict__ lfa, const float* __restrict__ gwts, const float* __restrict__ fwts,
    float* __restrict__ Qw, float* __restrict__ Kst, float* __restrict__ V, float* __restrict__ VP)
{
  int i = blockIdx.x, t = threadIdx.x;
  const float* pr = proj + (size_t)i*1632;
  float rx = rotvec[i*3], ry = rotvec[i*3+1], rz = rotvec[i*3+2];
  float nrm = sqrtf(rx*rx + ry*ry + rz*rz);
  float angle = nrm + 1e-8f;
  float inv = 1.0f / fmaxf(nrm, 1e-12f);
  float ax = rx*inv, ay = ry*inv, az = rz*inv;
  float f0 = fwts[0], f1 = fwts[1], f2 = fwts[2], f3 = fwts[3];
  float mfw = fmaxf(fmaxf(f0,f1), fmaxf(f2,f3));
  float e0 = expf(f0-mfw), e1 = expf(f1-mfw), e2 = expf(f2-mfw), e3 = expf(f3-mfw);
  float esum = e0+e1+e2+e3;
  float fw[4] = {e0/esum, e1/esum, e2/esum, e3/esum};
  float fq[4] = { 1.0f*expf(lfa[0]), 0.35355339059327373f*expf(lfa[1]),
                  0.125f*expf(lfa[2]), 0.04419417382415922f*expf(lfa[3]) };
  int h = t >> 4, g = t & 15;
  float gw = log1pf(expf(gwts[g])) * 0.25f;
  float q0 = pr[h*48 + g*3 + 0], q1 = pr[h*48 + g*3 + 1], q2 = pr[h*48 + g*3 + 2];
  float k0 = pr[384 + h*96 + g*3 + 0], k1 = pr[384 + h*96 + g*3 + 1], k2 = pr[384 + h*96 + g*3 + 2];
  #pragma unroll
  for (int f = 0; f < 4; f++){
    float th = angle * fq[f];
    float sn = sinf(th), cs = cosf(th), omc = 1.0f - cs;
    float r00 = cs + omc*ax*ax,       r01 = omc*ax*ay - sn*az,  r02 = omc*ax*az + sn*ay;
    float r10 = omc*ay*ax + sn*az,    r11 = cs + omc*ay*ay,     r12 = omc*ay*az - sn*ax;
    float r20 = omc*az*ax - sn*ay,    r21 = omc*az*ay + sn*ax,  r22 = cs + omc*az*az;
    float qr0 = r00*q0 + r01*q1 + r02*q2;
    float qr1 = r10*q0 + r11*q1 + r12*q2;
    float qr2 = r20*q0 + r21*q1 + r22*q2;
    float kr0 = r00*k0 + r01*k1 + r02*k2;
    float kr1 = r10*k0 + r11*k1 + r12*k2;
    float kr2 = r20*k0 + r21*k1 + r22*k2;
    float sc = fw[f] * gw * 0.57735026918962576f;
    int base = (h*512 + i)*192 + (g*4 + f)*3;
    Qw[base+0] = qr0*sc; Qw[base+1] = qr1*sc; Qw[base+2] = qr2*sc;
    Kst[base+0] = kr0;   Kst[base+1] = kr1;   Kst[base+2] = kr2;
  }
  for (int c = t; c < 384; c += 128){
    int hh = c / 48, cc = c % 48;
    V[(size_t)i*384 + c] = pr[384 + hh*96 + 48 + cc];
  }
  for (int qx = t; qx < 288; qx += 128){
    int ch = qx / 3, c3 = qx % 3;
    int hh = ch / 12, p = ch % 12;
    VP[(size_t)i*288 + qx] = pr[1152 + c3*160 + hh*20 + 8 + p];
  }
}

// ============ K3: z -> biasS only (sqrt(1/3) folded, layout [h][i][j]) ============
// block = (jt in 0..1, i); 37 KB LDS -> 4 blocks/CU. Plane-contiguous LDS layout.
__global__ __launch_bounds__(256) void zbias_kernel(
    const float* __restrict__ z, const float* __restrict__ wb, const float* __restrict__ bb,
    float* __restrict__ biasS)
{
  __shared__ float zs[8*1032];     // planes: kq in [0,8), each 256 j x 4 k words
  __shared__ float Wl[8*132];      // [ch][k]
  int i = blockIdx.y;
  int jt = blockIdx.x;
  int t = threadIdx.x;
  for (int r = 0; r < 4; r++){
    int e = t + 256*r;             // 1024 = 8ch*128k
    int ch = e & 7, k = e >> 3;
    Wl[ch*132 + k] = wb[k*8 + ch];
  }
  int cg = t >> 6, jg = t & 63;
  int ch0 = cg*2;
  float acc[2][4];
  #pragma unroll
  for (int c = 0; c < 2; c++)
    #pragma unroll
    for (int q = 0; q < 4; q++) acc[c][q] = 0.f;
  const float* zrow = z + ((size_t)i*512 + jt*256)*128;
  for (int kt = 0; kt < 4; kt++){
    __syncthreads();
    // stage: per instr lanes cover 64 consecutive j of one kq-plane (contiguous LDS write)
    #pragma unroll
    for (int r = 0; r < 8; r++){
      int j = (t & 63) + 64*(r & 3);
      int kq = (t >> 6) + 4*(r >> 2);
      float4 v = *(const float4*)(zrow + (size_t)j*128 + kt*32 + kq*4);
      *(float4*)&zs[kq*1032 + j*4] = v;
    }
    __syncthreads();
    const float* wl0 = Wl + ch0*132 + kt*32;
    const float* wl1 = wl0 + 132;
    #pragma unroll
    for (int kq = 0; kq < 8; kq++){
      float4 w0 = *(const float4*)(wl0 + kq*4);
      float4 w1 = *(const float4*)(wl1 + kq*4);
      #pragma unroll
      for (int q = 0; q < 4; q++){
        float4 zv = *(const float4*)&zs[kq*1032 + (q*64 + jg)*4];
        acc[0][q] = fmaf(zv.x, w0.x, acc[0][q]);
        acc[0][q] = fmaf(zv.y, w0.y, acc[0][q]);
        acc[0][q] = fmaf(zv.z, w0.z, acc[0][q]);
        acc[0][q] = fmaf(zv.w, w0.w, acc[0][q]);
        acc[1][q] = fmaf(zv.x, w1.x, acc[1][q]);
        acc[1][q] = fmaf(zv.y, w1.y, acc[1][q]);
        acc[1][q] = fmaf(zv.z, w1.z, acc[1][q]);
        acc[1][q] = fmaf(zv.w, w1.w, acc[1][q]);
      }
    }
  }
  float b0 = bb[ch0], b1 = bb[ch0+1];
  #pragma unroll
  for (int q = 0; q < 4; q++){
    int j = jt*256 + q*64 + jg;
    biasS[(size_t)ch0*262144 + i*512 + j]     = 0.57735026918962576f * (acc[0][q] + b0);
    biasS[(size_t)(ch0+1)*262144 + i*512 + j] = 0.57735026918962576f * (acc[1][q] + b1);
  }
}

// ============ K4: scores + bias + mask + softmax, in-place over biasS -> a ============
// block (i-tile 16, h); acc[4][8] held across k; Ks staged as contiguous k4-planes.
__global__ __launch_bounds__(256) void scores_kernel(
    const float* __restrict__ Qw, const float* __restrict__ Kst,
    const float* __restrict__ mask, float* A)
{
  __shared__ float Ks[4*2056];    // plane k4: 512 j x 4 k
  __shared__ float Qs[4*72];      // plane k4: 16 i x 4 k
  int i0 = blockIdx.x * 16;
  int h = blockIdx.y;
  int t = threadIdx.x;
  int ig = t >> 6, jl = t & 63;
  const float* Kb = Kst + (size_t)h*512*192;
  const float* Qb = Qw + (size_t)(h*512 + i0)*192;
  float acc[4][8];
  #pragma unroll
  for (int q = 0; q < 4; q++)
    #pragma unroll
    for (int jt = 0; jt < 8; jt++) acc[q][jt] = 0.f;
  for (int kc = 0; kc < 12; kc++){
    __syncthreads();
    {
      int k4 = t >> 6;            // wave stages its own plane; lanes j-contiguous
      #pragma unroll
      for (int r = 0; r < 8; r++){
        int j = (t & 63) + 64*r;
        float4 v = *(const float4*)(Kb + (size_t)j*192 + kc*16 + k4*4);
        *(float4*)&Ks[k4*2056 + j*4] = v;
      }
    }
    if (t < 64){
      int qi = t >> 2, k4 = t & 3;
      float4 v = *(const float4*)(Qb + (size_t)qi*192 + kc*16 + k4*4);
      *(float4*)&Qs[k4*72 + qi*4] = v;
    }
    __syncthreads();
    #pragma unroll
    for (int k4 = 0; k4 < 4; k4++){
      float4 qf[4];
      #pragma unroll
      for (int q = 0; q < 4; q++)
        qf[q] = *(const float4*)&Qs[k4*72 + (ig*4+q)*4];
      #pragma unroll
      for (int jt = 0; jt < 8; jt++){
        float4 kf = *(const float4*)&Ks[k4*2056 + (jt*64 + jl)*4];
        #pragma unroll
        for (int q = 0; q < 4; q++){
          acc[q][jt] = fmaf(qf[q].x, kf.x, acc[q][jt]);
          acc[q][jt] = fmaf(qf[q].y, kf.y, acc[q][jt]);
          acc[q][jt] = fmaf(qf[q].z, kf.z, acc[q][jt]);
          acc[q][jt] = fmaf(qf[q].w, kf.w, acc[q][jt]);
        }
      }
    }
  }
  int j0 = jl;
  float mj[8];
  #pragma unroll
  for (int jt = 0; jt < 8; jt++) mj[jt] = mask[jt*64 + j0];
  #pragma unroll
  for (int q = 0; q < 4; q++){
    int i = i0 + ig*4 + q;
    float mi = mask[i];
    #pragma unroll
    for (int jt = 0; jt < 8; jt++){
      float b = A[((size_t)h*512 + i)*512 + jt*64 + j0];
      acc[q][jt] += b + 100000.0f*(mi*mj[jt] - 1.0f);
    }
    float m = acc[q][0];
    #pragma unroll
    for (int jt = 1; jt < 8; jt++) m = fmaxf(m, acc[q][jt]);
    for (int off = 32; off > 0; off >>= 1) m = fmaxf(m, __shfl_xor(m, off));
    float ssum = 0.f;
    #pragma unroll
    for (int jt = 0; jt < 8; jt++){ acc[q][jt] = expf(acc[q][jt] - m); ssum += acc[q][jt]; }
    for (int off = 32; off > 0; off >>= 1) ssum += __shfl_xor(ssum, off);
    float invs = 1.0f / ssum;
    #pragma unroll
    for (int jt = 0; jt < 8; jt++){
      A[((size_t)h*512 + i)*512 + jt*64 + j0] = acc[q][jt] * invs;
    }
  }
}

// ============ K5a: Y = a@z per i, then o_pair = Y@wdz + bdz -> feats[768..1024) ============
// block = 2 i; thread owns (i_local, 2 h, 4 k). a in LDS [i][j][h] (b64 reads).
__global__ __launch_bounds__(256) void paircomb_kernel(
    const float* __restrict__ A, const float* __restrict__ z,
    const float* __restrict__ wdz, const float* __restrict__ bdz,
    float* __restrict__ feats)
{
  __shared__ float a_s[2*512*10];   // 40 KB
  __shared__ float Y_s[2*8*132];    // 8.4 KB
  int i0 = blockIdx.x * 2;
  int t = threadIdx.x;
  for (int r = 0; r < 32; r++){
    int e = t + 256*r;              // 8192 = 8h*2i*512j
    int hh = e >> 10, il = (e >> 9) & 1, j = e & 511;
    a_s[(il*512 + j)*10 + hh] = A[((size_t)hh*512 + i0 + il)*512 + j];
  }
  __syncthreads();
  int il = t >> 7, u = t & 127, hg = u >> 5, k4 = u & 31;
  const float* zb = z + ((size_t)(i0 + il)*512)*128 + k4*4;
  const float* asb = a_s + il*5120 + hg*2;
  float acc0[4], acc1[4];
  #pragma unroll
  for (int m = 0; m < 4; m++){ acc0[m] = 0.f; acc1[m] = 0.f; }
  #pragma unroll 8
  for (int j = 0; j < 512; j++){
    float2 a2 = *(const float2*)&asb[j*10];
    float4 zv = *(const float4*)(zb + (size_t)j*128);
    acc0[0] = fmaf(a2.x, zv.x, acc0[0]);
    acc0[1] = fmaf(a2.x, zv.y, acc0[1]);
    acc0[2] = fmaf(a2.x, zv.z, acc0[2]);
    acc0[3] = fmaf(a2.x, zv.w, acc0[3]);
    acc1[0] = fmaf(a2.y, zv.x, acc1[0]);
    acc1[1] = fmaf(a2.y, zv.y, acc1[1]);
    acc1[2] = fmaf(a2.y, zv.z, acc1[2]);
    acc1[3] = fmaf(a2.y, zv.w, acc1[3]);
  }
  float4 y0, y1;
  y0.x = acc0[0]; y0.y = acc0[1]; y0.z = acc0[2]; y0.w = acc0[3];
  y1.x = acc1[0]; y1.y = acc1[1]; y1.z = acc1[2]; y1.w = acc1[3];
  *(float4*)&Y_s[((il*8) + hg*2 + 0)*132 + k4*4] = y0;
  *(float4*)&Y_s[((il*8) + hg*2 + 1)*132 + k4*4] = y1;
  __syncthreads();
  {
    int il2 = t >> 7, u2 = t & 127, hh = u2 >> 4, cp = u2 & 15;
    const float* Yr = Y_s + (il2*8 + hh)*132;
    float s0 = bdz[cp*2], s1 = bdz[cp*2+1];
    #pragma unroll 8
    for (int k = 0; k < 128; k++){
      float yv = Yr[k];
      float2 w2 = *(const float2*)(wdz + (size_t)k*32 + cp*2);
      s0 = fmaf(yv, w2.x, s0);
      s1 = fmaf(yv, w2.y, s1);
    }
    float* fp = feats + (size_t)(i0 + il2)*1024 + 768 + hh*32 + cp*2;
    fp[0] = s0; fp[1] = s1;
  }
}

// ============ K5b: o (from V) + o_pt (from VP) + norms -> feats[0..768) ============
// block = 2 i; thread owns a float4 of the 672 channels (168 active threads).
__global__ __launch_bounds__(256) void ovcomb_kernel(
    const float* __restrict__ A, const float* __restrict__ V, const float* __restrict__ VP,
    float* __restrict__ feats)
{
  __shared__ float a_s2[8*64*2];    // [h][jj][i2]
  __shared__ float opt_s[2][292];
  int i0 = blockIdx.x * 2;
  int t = threadIdx.x;
  bool act = (t < 168);
  const float* base = V; int stride = 384; int hh = 0;
  if (act){
    int ch = t*4;
    if (ch < 384){ hh = ch/48; base = V + ch; stride = 384; }
    else { int qq = ch - 384; hh = qq/36; base = VP + qq; stride = 288; }
  }
  float acc0[4], acc1[4];
  #pragma unroll
  for (int m = 0; m < 4; m++){ acc0[m] = 0.f; acc1[m] = 0.f; }
  for (int jt = 0; jt < 8; jt++){
    __syncthreads();
    #pragma unroll
    for (int r = 0; r < 4; r++){
      int e = t + 256*r;            // 1024 = 8h*2i*64jj
      int eh = e >> 7, il = (e >> 6) & 1, jj = e & 63;
      a_s2[(eh*64 + jj)*2 + il] = A[((size_t)eh*512 + i0 + il)*512 + jt*64 + jj];
    }
    __syncthreads();
    if (act){
      const float* bj = base + (size_t)(jt*64)*stride;
      #pragma unroll 4
      for (int jj = 0; jj < 64; jj++){
        float2 a2 = *(const float2*)&a_s2[(hh*64 + jj)*2];
        float4 v4 = *(const float4*)(bj + (size_t)jj*stride);
        acc0[0] = fmaf(a2.x, v4.x, acc0[0]);
        acc0[1] = fmaf(a2.x, v4.y, acc0[1]);
        acc0[2] = fmaf(a2.x, v4.z, acc0[2]);
        acc0[3] = fmaf(a2.x, v4.w, acc0[3]);
        acc1[0] = fmaf(a2.y, v4.x, acc1[0]);
        acc1[1] = fmaf(a2.y, v4.y, acc1[1]);
        acc1[2] = fmaf(a2.y, v4.z, acc1[2]);
        acc1[3] = fmaf(a2.y, v4.w, acc1[3]);
      }
    }
  }
  if (act){
    int ch = t*4;
    if (ch < 384){
      float4 o0, o1;
      o0.x = acc0[0]; o0.y = acc0[1]; o0.z = acc0[2]; o0.w = acc0[3];
      o1.x = acc1[0]; o1.y = acc1[1]; o1.z = acc1[2]; o1.w = acc1[3];
      *(float4*)&feats[(size_t)i0*1024 + ch] = o0;
      *(float4*)&feats[(size_t)(i0+1)*1024 + ch] = o1;
    } else {
      int qq = ch - 384;
      #pragma unroll
      for (int m = 0; m < 4; m++){
        opt_s[0][qq + m] = acc0[m];
        opt_s[1][qq + m] = acc1[m];
      }
    }
  }
  __syncthreads();
  if (t < 192){
    int il = t / 96, p = t % 96;
    float x = opt_s[il][p*3], y = opt_s[il][p*3+1], zz = opt_s[il][p*3+2];
    float* fr = feats + (size_t)(i0 + il)*1024;
    fr[384 + p] = x;
    fr[480 + p] = y;
    fr[576 + p] = zz;
    fr[672 + p] = sqrtf(x*x + y*y + zz*zz + 1e-8f);
  }
}

// ============ K6: out = feats @ wout (+bout in reduce); split-K=8 partials ============
__global__ __launch_bounds__(256) void outgemm_kernel(
    const float* __restrict__ feats, const float* __restrict__ wout,
    float* __restrict__ part)
{
  __shared__ float fA[32*68];
  __shared__ float fB[32*68];
  int ct = blockIdx.x;            // 6
  int it = blockIdx.y;            // 8
  int sk = blockIdx.z;            // 8
  int i0 = it*64, c0 = ct*64, k0 = sk*128;
  int t = threadIdx.x;
  int ir = t >> 4, cr = t & 15;
  float acc[4][4];
  #pragma unroll
  for (int q = 0; q < 4; q++)
    #pragma unroll
    for (int p = 0; p < 4; p++) acc[q][p] = 0.f;
  for (int kt = 0; kt < 128; kt += 32){
    __syncthreads();
    #pragma unroll
    for (int r = 0; r < 2; r++){
      int e = t + 256*r;
      int i = e & 63, kq = e >> 6;  // kq 0..7
      float4 v = *(const float4*)(feats + (size_t)(i0 + i)*1024 + k0 + kt + kq*4);
      fA[(kq*4+0)*68 + i] = v.x; fA[(kq*4+1)*68 + i] = v.y;
      fA[(kq*4+2)*68 + i] = v.z; fA[(kq*4+3)*68 + i] = v.w;
    }
    #pragma unroll
    for (int r = 0; r < 2; r++){
      int e = t + 256*r;
      int kk = e >> 4, c4 = e & 15;
      float4 v = *(const float4*)(wout + (size_t)(k0 + kt + kk)*384 + c0 + c4*4);
      *(float4*)&fB[kk*68 + c4*4] = v;
    }
    __syncthreads();
    #pragma unroll 8
    for (int k = 0; k < 32; k++){
      float4 a4 = *(const float4*)&fA[k*68 + ir*4];
      float4 b4 = *(const float4*)&fB[k*68 + cr*4];
      acc[0][0] = fmaf(a4.x, b4.x, acc[0][0]);
      acc[0][1] = fmaf(a4.x, b4.y, acc[0][1]);
      acc[0][2] = fmaf(a4.x, b4.z, acc[0][2]);
      acc[0][3] = fmaf(a4.x, b4.w, acc[0][3]);
      acc[1][0] = fmaf(a4.y, b4.x, acc[1][0]);
      acc[1][1] = fmaf(a4.y, b4.y, acc[1][1]);
      acc[1][2] = fmaf(a4.y, b4.z, acc[1][2]);
      acc[1][3] = fmaf(a4.y, b4.w, acc[1][3]);
      acc[2][0] = fmaf(a4.z, b4.x, acc[2][0]);
      acc[2][1] = fmaf(a4.z, b4.y, acc[2][1]);
      acc[2][2] = fmaf(a4.z, b4.z, acc[2][2]);
      acc[2][3] = fmaf(a4.z, b4.w, acc[2][3]);
      acc[3][0] = fmaf(a4.w, b4.x, acc[3][0]);
      acc[3][1] = fmaf(a4.w, b4.y, acc[3][1]);
      acc[3][2] = fmaf(a4.w, b4.z, acc[3][2]);
      acc[3][3] = fmaf(a4.w, b4.w, acc[3][3]);
    }
  }
  float* pb = part + ((size_t)sk*512 + i0)*384 + c0;
  #pragma unroll
  for (int q = 0; q < 4; q++){
    float4 o;
    o.x = acc[q][0]; o.y = acc[q][1]; o.z = acc[q][2]; o.w = acc[q][3];
    *(float4*)&pb[(size_t)(ir*4 + q)*384 + cr*4] = o;
  }
}

__global__ __launch_bounds__(256) void outreduce_kernel(
    const float* __restrict__ part, const float* __restrict__ bout,
    float* __restrict__ out)
{
  int e = blockIdx.x*256 + threadIdx.x;     // 49152 float4s
  float4 acc = *(const float4*)(bout + (e % 96)*4);
  #pragma unroll
  for (int sk = 0; sk < 8; sk++){
    float4 p = *(const float4*)(part + (size_t)sk*196608 + (size_t)e*4);
    acc.x += p.x; acc.y += p.y; acc.z += p.z; acc.w += p.w;
  }
  *(float4*)(out + (size_t)e*4) = acc;
}

extern "C" void kernel_launch(void* const* d_in, const int* in_sizes, int n_in,
                              void* d_out, int out_size, void* d_ws, size_t ws_size,
                              hipStream_t stream)
{
  const float* s    = (const float*)d_in[0];
  const float* z    = (const float*)d_in[1];
  const float* rotv = (const float*)d_in[2];
  const float* mask = (const float*)d_in[3];
  const float* wq   = (const float*)d_in[4];
  const float* bq   = (const float*)d_in[5];
  const float* wkv  = (const float*)d_in[6];
  const float* bkv  = (const float*)d_in[7];
  const float* wkvp = (const float*)d_in[8];
  const float* bkvp = (const float*)d_in[9];
  const float* wb   = (const float*)d_in[10];
  const float* bb   = (const float*)d_in[11];
  const float* wdz  = (const float*)d_in[12];
  const float* bdz  = (const float*)d_in[13];
  const float* wout = (const float*)d_in[14];
  const float* bout = (const float*)d_in[15];
  const float* lfa  = (const float*)d_in[16];
  const float* gwts = (const float*)d_in[17];
  const float* fwts = (const float*)d_in[18];
  float* out = (float*)d_out;
  float* ws  = (float*)d_ws;

  float* proj  = ws + OFF_PROJ;
  float* Qw    = ws + OFF_QW;
  float* Kst   = ws + OFF_KST;
  float* V     = ws + OFF_V;
  float* VP    = ws + OFF_VP;
  float* A     = ws + OFF_A;     // biasS, overwritten in-place by softmax probs
  float* feats = ws + OFF_FEATS;
  float* part  = ws + OFF_PART;

  proj_kernel     <<<dim3(26, 16), 256, 0, stream>>>(s, wq, bq, wkv, bkv, wkvp, bkvp, proj);
  node_kernel     <<<dim3(512),    128, 0, stream>>>(proj, rotv, lfa, gwts, fwts, Qw, Kst, V, VP);
  zbias_kernel    <<<dim3(2, 512), 256, 0, stream>>>(z, wb, bb, A);
  scores_kernel   <<<dim3(32, 8),  256, 0, stream>>>(Qw, Kst, mask, A);
  paircomb_kernel <<<dim3(256),    256, 0, stream>>>(A, z, wdz, bdz, feats);
  ovcomb_kernel   <<<dim3(256),    256, 0, stream>>>(A, V, VP, feats);
  outgemm_kernel  <<<dim3(6, 8, 8),256, 0, stream>>>(feats, wout, part);
  outreduce_kernel<<<dim3(192),    256, 0, stream>>>(part, bout, out);
}